// Round 1
// baseline (6895.338 us; speedup 1.0000x reference)
//
#include <hip/hip_runtime.h>
#include <hip/hip_bf16.h>

// Problem constants
#define B_ 256
#define T_ 96
#define F_ 368
#define H_ 368
#define G3_ 1104          // 3*H
#define NC_ 29            // fine classes
#define G3PAD_ 1152       // 3*H padded to 288 float4 columns
#define BT_ (B_*T_)       // 24576

// ---------------------------------------------------------------------------
// K0: transpose Wh (1104x368) -> WhT (368x1152), zero-padding cols 1104..1151
// ---------------------------------------------------------------------------
__global__ __launch_bounds__(256) void k_transpose_wh(const float* __restrict__ Wh,
                                                      float* __restrict__ WhT) {
    __shared__ float tile[32][33];
    const int jb = blockIdx.x * 32;   // source row (gate-output) block: 0..1151
    const int kb = blockIdx.y * 32;   // source col (hidden) block: 0..367
    const int tx = threadIdx.x, ty = threadIdx.y; // 32 x 8
    for (int i = ty; i < 32; i += 8) {
        int j = jb + i, k = kb + tx;
        tile[i][tx] = (j < G3_ && k < F_) ? Wh[j*F_ + k] : 0.f;
    }
    __syncthreads();
    for (int i = ty; i < 32; i += 8) {
        int k = kb + i, j = jb + tx;
        if (k < F_ && j < G3PAD_) WhT[k*G3PAD_ + j] = tile[tx][i];
    }
}

// ---------------------------------------------------------------------------
// K1: xproj = features(24576x368) @ Wi^T(368x1104) + bi   (fp32, NT layout)
// 64x64 tile, BK=16, 256 threads, 4x4 micro-tile / thread.
// ---------------------------------------------------------------------------
__global__ __launch_bounds__(256) void k_xproj_gemm(const float* __restrict__ A,
                                                    const float* __restrict__ Bw,
                                                    const float* __restrict__ bias,
                                                    float* __restrict__ C) {
    __shared__ float As[16][68];   // [k][m], pad to 68 for 16B-aligned rows
    __shared__ float Bs[16][68];   // [k][n]
    const int tid = threadIdx.x;
    const int tx = tid & 15, ty = tid >> 4;
    const int bx = blockIdx.x;     // N tile (0..17)
    const int by = blockIdx.y;     // M tile (0..383)
    const int gm0 = by * 64, gn0 = bx * 64;

    const float4* A4 = reinterpret_cast<const float4*>(A);   // row stride 92
    const float4* B4 = reinterpret_cast<const float4*>(Bw);  // row stride 92

    const int lm = tid >> 2;       // 0..63 row within tile
    const int lkq = tid & 3;       // 0..3 float4 index within BK=16

    float acc[4][4];
    #pragma unroll
    for (int i = 0; i < 4; ++i)
        #pragma unroll
        for (int j = 0; j < 4; ++j) acc[i][j] = 0.f;

    for (int kt = 0; kt < 23; ++kt) {
        // load A tile
        {
            float4 v = A4[(size_t)(gm0 + lm)*92 + kt*4 + lkq];
            As[lkq*4+0][lm] = v.x; As[lkq*4+1][lm] = v.y;
            As[lkq*4+2][lm] = v.z; As[lkq*4+3][lm] = v.w;
        }
        // load B tile (guard n)
        {
            int gn = gn0 + lm;
            float4 v = make_float4(0.f,0.f,0.f,0.f);
            if (gn < G3_) v = B4[(size_t)gn*92 + kt*4 + lkq];
            Bs[lkq*4+0][lm] = v.x; Bs[lkq*4+1][lm] = v.y;
            Bs[lkq*4+2][lm] = v.z; Bs[lkq*4+3][lm] = v.w;
        }
        __syncthreads();
        #pragma unroll
        for (int k = 0; k < 16; ++k) {
            const float4 av = *reinterpret_cast<const float4*>(&As[k][ty*4]);
            const float4 bv = *reinterpret_cast<const float4*>(&Bs[k][tx*4]);
            const float a[4] = {av.x, av.y, av.z, av.w};
            const float b[4] = {bv.x, bv.y, bv.z, bv.w};
            #pragma unroll
            for (int i = 0; i < 4; ++i)
                #pragma unroll
                for (int j = 0; j < 4; ++j) acc[i][j] += a[i]*b[j];
        }
        __syncthreads();
    }
    #pragma unroll
    for (int i = 0; i < 4; ++i) {
        int gm = gm0 + ty*4 + i;
        #pragma unroll
        for (int j = 0; j < 4; ++j) {
            int gn = gn0 + tx*4 + j;
            if (gn < G3_) C[(size_t)gm*G3_ + gn] = acc[i][j] + bias[gn];
        }
    }
}

// ---------------------------------------------------------------------------
// K2: sequential GRU. 128 WGs x 2 batch rows, h in LDS, stream WhT from L2.
// ---------------------------------------------------------------------------
__global__ __launch_bounds__(256) void k_gru_seq(const float* __restrict__ xproj,
                                                 const float* __restrict__ WhT,
                                                 const float* __restrict__ bh,
                                                 float* __restrict__ temporal) {
    __shared__ float hsh[2][H_];
    __shared__ float ghs[2][G3PAD_];
    __shared__ float bhs[G3_];
    const int tid = threadIdx.x;
    const int r0 = blockIdx.x * 2;

    for (int i = tid; i < 2*H_; i += 256) (&hsh[0][0])[i] = 0.f;
    for (int i = tid; i < G3_;  i += 256) bhs[i] = bh[i];
    __syncthreads();

    const int w = tid >> 6, l = tid & 63;
    const int c0 = w*72 + l;            // float4 column, 288 cols over 4 waves
    const int c1 = w*72 + 64 + l;       // second column for lanes l<8
    const bool has2 = (l < 8);
    const float4* WT4 = reinterpret_cast<const float4*>(WhT); // row stride 288

    for (int t = 0; t < T_; ++t) {
        // ---- phase 1: gh[r][:] = h[r] @ Wh^T  (via WhT rank-1 updates) ----
        float4 a00 = make_float4(0,0,0,0), a10 = a00, a01 = a00, a11 = a00;
        const float4* p = WT4;
        for (int k = 0; k < H_; ++k) {
            const float h0 = hsh[0][k], h1 = hsh[1][k];
            const float4 wv = p[c0];
            a00.x += wv.x*h0; a00.y += wv.y*h0; a00.z += wv.z*h0; a00.w += wv.w*h0;
            a10.x += wv.x*h1; a10.y += wv.y*h1; a10.z += wv.z*h1; a10.w += wv.w*h1;
            if (has2) {
                const float4 wv2 = p[c1];
                a01.x += wv2.x*h0; a01.y += wv2.y*h0; a01.z += wv2.z*h0; a01.w += wv2.w*h0;
                a11.x += wv2.x*h1; a11.y += wv2.y*h1; a11.z += wv2.z*h1; a11.w += wv2.w*h1;
            }
            p += 288;
        }
        reinterpret_cast<float4*>(&ghs[0][0])[c0] = a00;
        reinterpret_cast<float4*>(&ghs[1][0])[c0] = a10;
        if (has2) {
            reinterpret_cast<float4*>(&ghs[0][0])[c1] = a01;
            reinterpret_cast<float4*>(&ghs[1][0])[c1] = a11;
        }
        __syncthreads();
        // ---- phase 2: gates + h update + write temporal ----
        const float* x0 = xproj + (size_t)(r0*T_ + t)*G3_;
        for (int j = tid; j < H_; j += 256) {
            #pragma unroll
            for (int r = 0; r < 2; ++r) {
                const float* xr = x0 + (size_t)r*T_*G3_;
                const float gir = xr[j], giz = xr[H_+j], gin = xr[2*H_+j];
                const float ghr = ghs[r][j]      + bhs[j];
                const float ghz = ghs[r][H_+j]   + bhs[H_+j];
                const float ghn = ghs[r][2*H_+j] + bhs[2*H_+j];
                const float rg = 1.f/(1.f + expf(-(gir+ghr)));
                const float zg = 1.f/(1.f + expf(-(giz+ghz)));
                const float ng = tanhf(gin + rg*ghn);
                const float hn = (1.f - zg)*ng + zg*hsh[r][j];
                hsh[r][j] = hn;
                temporal[((size_t)(r0 + r)*T_ + t)*H_ + j] = hn;
            }
        }
        __syncthreads();
    }
}

// ---------------------------------------------------------------------------
// K3: heads. 8 rows/block: logits = temporal_row @ [Wc;Wf]^T + [bc;bf],
// coarse softmax -> cs (ws), fine sigmoid -> d_out fine region.
// ---------------------------------------------------------------------------
__global__ __launch_bounds__(256) void k_heads(const float* __restrict__ temporal,
                                               const float* __restrict__ Wc,
                                               const float* __restrict__ bc,
                                               const float* __restrict__ Wf,
                                               const float* __restrict__ bf,
                                               float* __restrict__ cs,
                                               float* __restrict__ fine_out) {
    __shared__ float rowbuf[8*F_];      // 8 temporal rows
    __shared__ float Wl[31*372];        // rows 0-1 Wc, 2-30 Wf; stride 372
    __shared__ float lg[8][31];
    const int tid = threadIdx.x;
    const size_t row0 = (size_t)blockIdx.x * 8;

    for (int i = tid; i < 8*F_; i += 256) rowbuf[i] = temporal[row0*F_ + i];
    for (int i = tid; i < 31*F_; i += 256) {
        int r = i / F_, k = i - r*F_;
        Wl[r*372 + k] = (r < 2) ? Wc[i] : Wf[i - 2*F_];
    }
    __syncthreads();
    if (tid < 248) {
        const int r = tid / 31, c = tid - r*31;
        float acc = (c < 2) ? bc[c] : bf[c-2];
        const float4* wp = reinterpret_cast<const float4*>(&Wl[c*372]);
        const float4* xp = reinterpret_cast<const float4*>(&rowbuf[r*F_]);
        for (int k = 0; k < F_/4; ++k) {
            const float4 xv = xp[k], wv = wp[k];
            acc += xv.x*wv.x + xv.y*wv.y + xv.z*wv.z + xv.w*wv.w;
        }
        lg[r][c] = acc;
    }
    __syncthreads();
    if (tid < 248) {
        const int r = tid / 31, c = tid - r*31;
        const size_t row = row0 + r;
        if (c == 0) {
            const float l0 = lg[r][0], l1 = lg[r][1];
            const float m = fmaxf(l0, l1);
            const float e0 = expf(l0 - m), e1 = expf(l1 - m);
            const float inv = 1.f/(e0 + e1);
            cs[row*2]   = e0*inv;
            cs[row*2+1] = e1*inv;
        } else if (c >= 2) {
            fine_out[row*NC_ + (c-2)] = 1.f/(1.f + expf(-lg[r][c]));
        }
    }
}

// ---------------------------------------------------------------------------
// K4: sliding-window-min NMS + argmax decisions.
// keep iff bg[t] <= min over clipped window [t-2, t+2].
// ---------------------------------------------------------------------------
__global__ __launch_bounds__(256) void k_nms(const float* __restrict__ cs,
                                             float* __restrict__ out_dec,
                                             float* __restrict__ out_nms) {
    const int idx = blockIdx.x*256 + threadIdx.x;   // < 24576
    const int t = idx % T_;
    const float bg = cs[idx*2], s1 = cs[idx*2+1];
    float wmin = bg;
    #pragma unroll
    for (int dt = -2; dt <= 2; ++dt) {
        const int tt = t + dt;
        if (dt != 0 && tt >= 0 && tt < T_) wmin = fminf(wmin, cs[(idx + dt)*2]);
    }
    const bool keep = (bg <= wmin);
    out_dec[idx]     = (keep && (s1 > bg)) ? 1.f : 0.f;
    out_nms[idx*2]   = keep ? bg : 0.f;
    out_nms[idx*2+1] = keep ? s1 : 0.f;
}

// ---------------------------------------------------------------------------
extern "C" void kernel_launch(void* const* d_in, const int* in_sizes, int n_in,
                              void* d_out, int out_size, void* d_ws, size_t ws_size,
                              hipStream_t stream) {
    const float* features = (const float*)d_in[0];
    // d_in[1] = hand (unused by reference forward)
    const float* Wi = (const float*)d_in[2];
    const float* Wh = (const float*)d_in[3];
    const float* bi = (const float*)d_in[4];
    const float* bh = (const float*)d_in[5];
    const float* Wc = (const float*)d_in[6];
    const float* bc = (const float*)d_in[7];
    const float* Wf = (const float*)d_in[8];
    const float* bf = (const float*)d_in[9];

    float* out = (float*)d_out;
    float* out_dec  = out;                 // (B,T)     24576
    float* out_nms  = out + BT_;           // (B,T,2)   49152
    float* out_fine = out + BT_ + 2*BT_;   // (B,T,29)  712704

    // workspace layout (floats): xproj | WhT | temporal | cs  (~147 MB total)
    float* xproj    = (float*)d_ws;                  // 24576*1104 = 27,131,904
    float* WhT      = xproj + (size_t)BT_*G3_;       // 368*1152   =    423,936
    float* temporal = WhT + (size_t)F_*G3PAD_;       // 24576*368  =  9,043,968
    float* cs       = temporal + (size_t)BT_*H_;     // 24576*2    =     49,152

    k_transpose_wh<<<dim3(36,12), dim3(32,8), 0, stream>>>(Wh, WhT);
    k_xproj_gemm<<<dim3(18,384), 256, 0, stream>>>(features, Wi, bi, xproj);
    k_gru_seq<<<128, 256, 0, stream>>>(xproj, WhT, bh, temporal);
    k_heads<<<3072, 256, 0, stream>>>(temporal, Wc, bc, Wf, bf, cs, out_fine);
    k_nms<<<96, 256, 0, stream>>>(cs, out_dec, out_nms);
}

// Round 2
// 1873.303 us; speedup vs baseline: 3.6808x; 3.6808x over previous
//
#include <hip/hip_runtime.h>
#include <hip/hip_bf16.h>

// Problem constants
#define B_ 256
#define T_ 96
#define F_ 368
#define H_ 368
#define G3_ 1104          // 3*H
#define NC_ 29            // fine classes
#define BT_ (B_*T_)       // 24576
#define HB_ (H_*B_)       // 94208, one time-slice of temporal [u][b]

// GRU step-kernel geometry
#define NSL 8             // unit slices
#define NU 46             // units per slice (8*46 = 368)
#define NCOL 138          // cols per slice = 3*NU
#define SLSTRIDE 144      // padded col positions per slice (64+64+16)
#define WQCOLS 1152       // 8 * 144
#define NBG 32            // batch groups
#define ROWS 8            // rows per batch group

#define F4C(v, i) ((i)==0?(v).x:((i)==1?(v).y:((i)==2?(v).z:(v).w)))

// ---------------------------------------------------------------------------
// K0: pack Wh (1104x368) into Wq: float4 blocks [kb=92][1152 colpos],
// Wq[kb][cp] = Wh[grow(cp)][4kb..4kb+3]. Col positions per slice:
//   0..63 -> cols 0..63, 64..127 -> cols 64..127, 128..143 -> cols 128..143
//   (real cols 0..137 = g*46+u for gate g, unit u; 138..143 zero pad)
// ---------------------------------------------------------------------------
__global__ __launch_bounds__(256) void k_prep_wq(const float* __restrict__ Wh,
                                                 float4* __restrict__ Wq) {
    const int idx = blockIdx.x*256 + threadIdx.x;   // < 92*1152 = 105984
    const int kb = idx / WQCOLS, cp = idx - kb*WQCOLS;
    const int us = cp / SLSTRIDE, r = cp - us*SLSTRIDE;
    float4 v = make_float4(0.f,0.f,0.f,0.f);
    if (r < NCOL) {
        const int g = r / NU, u = r - g*NU;
        const int grow = g*H_ + us*NU + u;          // < 1104
        v = *reinterpret_cast<const float4*>(Wh + (size_t)grow*H_ + 4*kb);
    }
    Wq[idx] = v;
}

// ---------------------------------------------------------------------------
// K0b: pack head weights: Wcat[u][32]: c<2 -> Wc[c][u], c in 2..30 -> Wf[c-2][u]
// ---------------------------------------------------------------------------
__global__ __launch_bounds__(256) void k_prep_wcat(const float* __restrict__ Wc,
                                                   const float* __restrict__ Wf,
                                                   float* __restrict__ Wcat) {
    const int idx = blockIdx.x*256 + threadIdx.x;   // < 368*32 = 11776
    const int u = idx >> 5, c = idx & 31;
    float v = 0.f;
    if (c < 2) v = Wc[c*H_ + u];
    else if (c < 31) v = Wf[(c-2)*H_ + u];
    Wcat[idx] = v;
}

// ---------------------------------------------------------------------------
// K1: xproj = features(24576x368) @ Wi^T(368x1104) + bi   (fp32, NT layout)
// (unchanged from passing round-0)
// ---------------------------------------------------------------------------
__global__ __launch_bounds__(256) void k_xproj_gemm(const float* __restrict__ A,
                                                    const float* __restrict__ Bw,
                                                    const float* __restrict__ bias,
                                                    float* __restrict__ C) {
    __shared__ float As[16][68];
    __shared__ float Bs[16][68];
    const int tid = threadIdx.x;
    const int tx = tid & 15, ty = tid >> 4;
    const int bx = blockIdx.x;
    const int by = blockIdx.y;
    const int gm0 = by * 64, gn0 = bx * 64;

    const float4* A4 = reinterpret_cast<const float4*>(A);
    const float4* B4 = reinterpret_cast<const float4*>(Bw);

    const int lm = tid >> 2;
    const int lkq = tid & 3;

    float acc[4][4];
    #pragma unroll
    for (int i = 0; i < 4; ++i)
        #pragma unroll
        for (int j = 0; j < 4; ++j) acc[i][j] = 0.f;

    for (int kt = 0; kt < 23; ++kt) {
        {
            float4 v = A4[(size_t)(gm0 + lm)*92 + kt*4 + lkq];
            As[lkq*4+0][lm] = v.x; As[lkq*4+1][lm] = v.y;
            As[lkq*4+2][lm] = v.z; As[lkq*4+3][lm] = v.w;
        }
        {
            int gn = gn0 + lm;
            float4 v = make_float4(0.f,0.f,0.f,0.f);
            if (gn < G3_) v = B4[(size_t)gn*92 + kt*4 + lkq];
            Bs[lkq*4+0][lm] = v.x; Bs[lkq*4+1][lm] = v.y;
            Bs[lkq*4+2][lm] = v.z; Bs[lkq*4+3][lm] = v.w;
        }
        __syncthreads();
        #pragma unroll
        for (int k = 0; k < 16; ++k) {
            const float4 av = *reinterpret_cast<const float4*>(&As[k][ty*4]);
            const float4 bv = *reinterpret_cast<const float4*>(&Bs[k][tx*4]);
            const float a[4] = {av.x, av.y, av.z, av.w};
            const float b[4] = {bv.x, bv.y, bv.z, bv.w};
            #pragma unroll
            for (int i = 0; i < 4; ++i)
                #pragma unroll
                for (int j = 0; j < 4; ++j) acc[i][j] += a[i]*b[j];
        }
        __syncthreads();
    }
    #pragma unroll
    for (int i = 0; i < 4; ++i) {
        int gm = gm0 + ty*4 + i;
        #pragma unroll
        for (int j = 0; j < 4; ++j) {
            int gn = gn0 + tx*4 + j;
            if (gn < G3_) C[(size_t)gm*G3_ + gn] = acc[i][j] + bias[gn];
        }
    }
}

// ---------------------------------------------------------------------------
// K2: one GRU time step. Grid = 256 WGs = 32 batch-groups x 8 unit-slices,
// XCD-pinned. h = temporal[t-1] (layout [t][u][b], wave-uniform s_loads);
// W per-lane coalesced from Wq (L2-resident). 4 waves split K (quarters),
// partials reduced through LDS, gates fused (slice owns r/z/n col triples).
// Writes h(t) = temporal[t] slice.
// ---------------------------------------------------------------------------
__global__ __launch_bounds__(256) void k_gru_step(const float* __restrict__ xproj,
                                                  const float4* __restrict__ Wq,
                                                  const float* __restrict__ bh,
                                                  float* __restrict__ temporal,
                                                  int t_) {
    __shared__ float part[4][ROWS][SLSTRIDE];   // 18,432 B
    const int tid = threadIdx.x;
    const int xcd = blockIdx.x & 7;
    const int j   = blockIdx.x >> 3;            // 0..31
    const int bg  = 4*xcd + (j >> 3);           // 0..31
    const int us  = j & 7;                      // 0..7
    const int b0  = bg * ROWS;
    const int wq  = __builtin_amdgcn_readfirstlane(tid >> 6);  // k-quarter
    const int l   = tid & 63;
    const int l3  = 128 + (l & 15);

    const float* hin  = temporal + (size_t)(t_ - 1)*HB_;   // only deref'd if t_>0
    float*       hout = temporal + (size_t)t_*HB_;

    float acc[ROWS][3];
    #pragma unroll
    for (int r = 0; r < ROWS; ++r) { acc[r][0]=0.f; acc[r][1]=0.f; acc[r][2]=0.f; }

    if (t_ > 0) {
        const float*  hq = hin + (size_t)(wq*92)*B_ + b0;          // uniform base
        const float4* wp = Wq + (size_t)(wq*23)*WQCOLS + us*SLSTRIDE;
        for (int kk = 0; kk < 23; ++kk) {
            // 8 wave-uniform float4 loads -> SGPRs (h for 4 k's x 8 rows)
            float4 h0[4], h1[4];
            #pragma unroll
            for (int jk = 0; jk < 4; ++jk) {
                const float* hp = hq + (size_t)(kk*4 + jk)*B_;
                h0[jk] = *reinterpret_cast<const float4*>(hp);
                h1[jk] = *reinterpret_cast<const float4*>(hp + 4);
            }
            // 3 per-lane coalesced b128 loads of W (4 k's each)
            const float4 w0 = wp[(size_t)kk*WQCOLS + l];
            const float4 w1 = wp[(size_t)kk*WQCOLS + 64 + l];
            const float4 w2 = wp[(size_t)kk*WQCOLS + l3];
            #pragma unroll
            for (int jk = 0; jk < 4; ++jk) {
                const float wa = F4C(w0, jk), wb = F4C(w1, jk), wc = F4C(w2, jk);
                #pragma unroll
                for (int r = 0; r < 4; ++r) {
                    const float hv = F4C(h0[jk], r);
                    acc[r][0] = fmaf(hv, wa, acc[r][0]);
                    acc[r][1] = fmaf(hv, wb, acc[r][1]);
                    acc[r][2] = fmaf(hv, wc, acc[r][2]);
                }
                #pragma unroll
                for (int r = 0; r < 4; ++r) {
                    const float hv = F4C(h1[jk], r);
                    acc[4+r][0] = fmaf(hv, wa, acc[4+r][0]);
                    acc[4+r][1] = fmaf(hv, wb, acc[4+r][1]);
                    acc[4+r][2] = fmaf(hv, wc, acc[4+r][2]);
                }
            }
        }
    }
    // write k-quarter partials (block3 lanes l, l+16, l+32, l+48 write same value)
    #pragma unroll
    for (int r = 0; r < ROWS; ++r) {
        part[wq][r][l]      = acc[r][0];
        part[wq][r][64 + l] = acc[r][1];
        part[wq][r][l3]     = acc[r][2];
    }
    __syncthreads();
    // fused gates: items = 8 rows x 46 units = 368
    for (int i = tid; i < ROWS*NU; i += 256) {
        const int u = i % NU, r = i / NU;
        const int ug = us*NU + u;
        const int b  = b0 + r;
        float s0 = part[0][r][u]        + part[1][r][u]        + part[2][r][u]        + part[3][r][u];
        float s1 = part[0][r][NU+u]     + part[1][r][NU+u]     + part[2][r][NU+u]     + part[3][r][NU+u];
        float s2 = part[0][r][2*NU+u]   + part[1][r][2*NU+u]   + part[2][r][2*NU+u]   + part[3][r][2*NU+u];
        const float* xr = xproj + ((size_t)b*T_ + t_)*G3_;
        const float gir = xr[ug], giz = xr[H_+ug], gin = xr[2*H_+ug];
        const float ghr = s0 + bh[ug];
        const float ghz = s1 + bh[H_+ug];
        const float ghn = s2 + bh[2*H_+ug];
        const float rg = 1.f/(1.f + expf(-(gir+ghr)));
        const float zg = 1.f/(1.f + expf(-(giz+ghz)));
        const float ng = tanhf(gin + rg*ghn);
        const float hp = (t_ > 0) ? hin[(size_t)ug*B_ + b] : 0.f;
        const float hn = (1.f - zg)*ng + zg*hp;
        hout[(size_t)ug*B_ + b] = hn;
    }
}

// ---------------------------------------------------------------------------
// K3: heads on temporal [t][u][b]: block = t, thread = batch row.
// Wcat rows via wave-uniform s_loads; temporal reads coalesced over b.
// ---------------------------------------------------------------------------
__global__ __launch_bounds__(256) void k_heads2(const float* __restrict__ temporal,
                                                const float* __restrict__ Wcat,
                                                const float* __restrict__ bc,
                                                const float* __restrict__ bf,
                                                float* __restrict__ cs,
                                                float* __restrict__ fine_out) {
    const int t = blockIdx.x;       // 0..95
    const int b = threadIdx.x;      // 0..255
    const float* tb = temporal + (size_t)t*HB_ + b;
    float acc[31];
    #pragma unroll
    for (int c = 0; c < 31; ++c) acc[c] = 0.f;
    for (int u = 0; u < H_; ++u) {
        const float x = tb[(size_t)u*B_];
        const float* wrow = Wcat + u*32;     // uniform -> s_load
        #pragma unroll
        for (int c = 0; c < 31; ++c) acc[c] = fmaf(x, wrow[c], acc[c]);
    }
    const float l0 = acc[0] + bc[0], l1 = acc[1] + bc[1];
    const float m  = fmaxf(l0, l1);
    const float e0 = expf(l0 - m), e1 = expf(l1 - m);
    const float inv = 1.f/(e0 + e1);
    cs[((size_t)b*T_ + t)*2]     = e0*inv;
    cs[((size_t)b*T_ + t)*2 + 1] = e1*inv;
    #pragma unroll
    for (int c = 2; c < 31; ++c) {
        fine_out[((size_t)b*T_ + t)*NC_ + (c-2)] = 1.f/(1.f + expf(-(acc[c] + bf[c-2])));
    }
}

// ---------------------------------------------------------------------------
// K4: sliding-window-min NMS + argmax decisions (unchanged, passing)
// ---------------------------------------------------------------------------
__global__ __launch_bounds__(256) void k_nms(const float* __restrict__ cs,
                                             float* __restrict__ out_dec,
                                             float* __restrict__ out_nms) {
    const int idx = blockIdx.x*256 + threadIdx.x;   // < 24576
    const int t = idx % T_;
    const float bg = cs[idx*2], s1 = cs[idx*2+1];
    float wmin = bg;
    #pragma unroll
    for (int dt = -2; dt <= 2; ++dt) {
        const int tt = t + dt;
        if (dt != 0 && tt >= 0 && tt < T_) wmin = fminf(wmin, cs[(idx + dt)*2]);
    }
    const bool keep = (bg <= wmin);
    out_dec[idx]     = (keep && (s1 > bg)) ? 1.f : 0.f;
    out_nms[idx*2]   = keep ? bg : 0.f;
    out_nms[idx*2+1] = keep ? s1 : 0.f;
}

// ---------------------------------------------------------------------------
extern "C" void kernel_launch(void* const* d_in, const int* in_sizes, int n_in,
                              void* d_out, int out_size, void* d_ws, size_t ws_size,
                              hipStream_t stream) {
    const float* features = (const float*)d_in[0];
    const float* Wi = (const float*)d_in[2];
    const float* Wh = (const float*)d_in[3];
    const float* bi = (const float*)d_in[4];
    const float* bh = (const float*)d_in[5];
    const float* Wc = (const float*)d_in[6];
    const float* bc = (const float*)d_in[7];
    const float* Wf = (const float*)d_in[8];
    const float* bf = (const float*)d_in[9];

    float* out = (float*)d_out;
    float* out_dec  = out;                 // (B,T)     24576
    float* out_nms  = out + BT_;           // (B,T,2)   49152
    float* out_fine = out + BT_ + 2*BT_;   // (B,T,29)  712704

    // workspace (floats), total 36,599,808 = 146.4 MB (<= round-0 footprint):
    //   xproj    [0,            27,131,904)
    //   Wq       [27,131,904,   27,555,840)   92*1152 float4
    //   temporal [27,555,840,   36,599,808)   [t][u][b]
    // after GRU steps, xproj region is dead -> reuse for Wcat + cs:
    //   Wcat = ws + 0           (11,776)
    //   cs   = ws + 12,288      (98,304)
    float* xproj    = (float*)d_ws;
    float4* Wq      = (float4*)(xproj + (size_t)BT_*G3_);
    float* temporal = xproj + (size_t)BT_*G3_ + (size_t)92*WQCOLS*4;
    float* Wcat     = xproj;
    float* cs       = xproj + 12288;

    k_prep_wq<<<414, 256, 0, stream>>>(Wh, Wq);
    k_xproj_gemm<<<dim3(18,384), 256, 0, stream>>>(features, Wi, bi, xproj);
    for (int t = 0; t < T_; ++t) {
        k_gru_step<<<256, 256, 0, stream>>>(xproj, Wq, bh, temporal, t);
    }
    k_prep_wcat<<<46, 256, 0, stream>>>(Wc, Wf, Wcat);
    k_heads2<<<96, 256, 0, stream>>>(temporal, Wcat, bc, bf, cs, out_fine);
    k_nms<<<96, 256, 0, stream>>>(cs, out_dec, out_nms);
}

// Round 3
// 1368.647 us; speedup vs baseline: 5.0381x; 1.3687x over previous
//
#include <hip/hip_runtime.h>
#include <hip/hip_bf16.h>

// Problem constants
#define B_ 256
#define T_ 96
#define F_ 368
#define H_ 368
#define G3_ 1104          // 3*H
#define NC_ 29            // fine classes
#define BT_ (B_*T_)       // 24576
#define HB_ (H_*B_)       // 94208, one time-slice of temporal [u][b]

// GRU step-kernel geometry
#define NSL 8             // unit slices
#define NU 46             // units per slice (8*46 = 368)
#define NCOL 138          // cols per slice = 3*NU
#define SLSTRIDE 144      // padded col positions per slice (64+64+16)
#define WQCOLS 1152       // 8 * 144
#define ROWS 8            // rows per batch group

#define F4C(v, i) ((i)==0?(v).x:((i)==1?(v).y:((i)==2?(v).z:(v).w)))

// ---------------------------------------------------------------------------
// K0: pack Wh (1104x368) into Wq float4 blocks [kb=92][1152 colpos]
// (unchanged from passing round-2)
// ---------------------------------------------------------------------------
__global__ __launch_bounds__(256) void k_prep_wq(const float* __restrict__ Wh,
                                                 float4* __restrict__ Wq) {
    const int idx = blockIdx.x*256 + threadIdx.x;   // < 92*1152 = 105984
    const int kb = idx / WQCOLS, cp = idx - kb*WQCOLS;
    const int us = cp / SLSTRIDE, r = cp - us*SLSTRIDE;
    float4 v = make_float4(0.f,0.f,0.f,0.f);
    if (r < NCOL) {
        const int g = r / NU, u = r - g*NU;
        const int grow = g*H_ + us*NU + u;          // < 1104
        v = *reinterpret_cast<const float4*>(Wh + (size_t)grow*H_ + 4*kb);
    }
    Wq[idx] = v;
}

// ---------------------------------------------------------------------------
// K0b: pack head weights Wcat[u][32] (unchanged)
// ---------------------------------------------------------------------------
__global__ __launch_bounds__(256) void k_prep_wcat(const float* __restrict__ Wc,
                                                   const float* __restrict__ Wf,
                                                   float* __restrict__ Wcat) {
    const int idx = blockIdx.x*256 + threadIdx.x;   // < 368*32 = 11776
    const int u = idx >> 5, c = idx & 31;
    float v = 0.f;
    if (c < 2) v = Wc[c*H_ + u];
    else if (c < 31) v = Wf[(c-2)*H_ + u];
    Wcat[idx] = v;
}

// ---------------------------------------------------------------------------
// K1 v2: xproj = features(24576x368) @ Wi^T(368x1104) + bi   (fp32)
// 128x128 tile, BK=16, 256 threads, 8x8 split micro-tile (4+4, halves 64
// apart -> LDS reads are broadcast / 2-way only). 64 FMA per 4 ds_read_b128.
// ---------------------------------------------------------------------------
__global__ __launch_bounds__(256) void k_xproj_gemm(const float* __restrict__ A,
                                                    const float* __restrict__ Bw,
                                                    const float* __restrict__ bias,
                                                    float* __restrict__ C) {
    __shared__ float As[16][128];
    __shared__ float Bs[16][128];
    const int tid = threadIdx.x;
    const int tx = tid & 15, ty = tid >> 4;
    const int gm0 = blockIdx.y * 128, gn0 = blockIdx.x * 128;
    const float4* A4 = reinterpret_cast<const float4*>(A);   // row stride 92
    const float4* B4 = reinterpret_cast<const float4*>(Bw);
    const int lm = tid & 127;           // tile row/col this thread stages
    const int kh = (tid >> 7) * 2;      // float4-k offset: 0 or 2

    float acc[8][8];
    #pragma unroll
    for (int i = 0; i < 8; ++i)
        #pragma unroll
        for (int j = 0; j < 8; ++j) acc[i][j] = 0.f;

    for (int kt = 0; kt < 23; ++kt) {
        // global loads into regs
        float4 va[2], vb[2];
        #pragma unroll
        for (int q = 0; q < 2; ++q)
            va[q] = A4[(size_t)(gm0 + lm)*92 + kt*4 + kh + q];
        const int gn = gn0 + lm;
        #pragma unroll
        for (int q = 0; q < 2; ++q)
            vb[q] = (gn < G3_) ? B4[(size_t)gn*92 + kt*4 + kh + q]
                               : make_float4(0.f,0.f,0.f,0.f);
        __syncthreads();   // previous iteration's LDS reads done
        #pragma unroll
        for (int q = 0; q < 2; ++q) {
            As[(kh+q)*4+0][lm] = va[q].x; As[(kh+q)*4+1][lm] = va[q].y;
            As[(kh+q)*4+2][lm] = va[q].z; As[(kh+q)*4+3][lm] = va[q].w;
            Bs[(kh+q)*4+0][lm] = vb[q].x; Bs[(kh+q)*4+1][lm] = vb[q].y;
            Bs[(kh+q)*4+2][lm] = vb[q].z; Bs[(kh+q)*4+3][lm] = vb[q].w;
        }
        __syncthreads();
        #pragma unroll
        for (int k = 0; k < 16; ++k) {
            const float4 a0 = *reinterpret_cast<const float4*>(&As[k][ty*4]);
            const float4 a1 = *reinterpret_cast<const float4*>(&As[k][64 + ty*4]);
            const float4 b0 = *reinterpret_cast<const float4*>(&Bs[k][tx*4]);
            const float4 b1 = *reinterpret_cast<const float4*>(&Bs[k][64 + tx*4]);
            #pragma unroll
            for (int i = 0; i < 4; ++i) {
                const float ai0 = F4C(a0, i), ai1 = F4C(a1, i);
                #pragma unroll
                for (int j = 0; j < 4; ++j) {
                    const float bj0 = F4C(b0, j), bj1 = F4C(b1, j);
                    acc[i][j]     = fmaf(ai0, bj0, acc[i][j]);
                    acc[i][j+4]   = fmaf(ai0, bj1, acc[i][j+4]);
                    acc[i+4][j]   = fmaf(ai1, bj0, acc[i+4][j]);
                    acc[i+4][j+4] = fmaf(ai1, bj1, acc[i+4][j+4]);
                }
            }
        }
    }
    #pragma unroll
    for (int i = 0; i < 8; ++i) {
        const int gm = gm0 + ((i < 4) ? (ty*4 + i) : (64 + ty*4 + i - 4));
        #pragma unroll
        for (int j = 0; j < 8; ++j) {
            const int gn = gn0 + ((j < 4) ? (tx*4 + j) : (64 + tx*4 + j - 4));
            if (gn < G3_) C[(size_t)gm*G3_ + gn] = acc[i][j] + bias[gn];
        }
    }
}

// ---------------------------------------------------------------------------
// K2 v2: one GRU time step. Grid 256 = 32 bg x 8 slices, XCD-pinned.
// h(t-1) block staged into LDS once (coalesced), W software-pipelined from
// L2, gate-phase xproj/bh operands prefetched at entry.
// ---------------------------------------------------------------------------
__global__ __launch_bounds__(256) void k_gru_step(const float* __restrict__ xproj,
                                                  const float4* __restrict__ Wq,
                                                  const float* __restrict__ bh,
                                                  float* __restrict__ temporal,
                                                  int t_) {
    __shared__ float part[4][ROWS][SLSTRIDE];   // 18,432 B
    __shared__ float hsl[H_*ROWS];              // h(t-1)[k][r], 11,776 B
    const int tid = threadIdx.x;
    const int xcd = blockIdx.x & 7;
    const int j   = blockIdx.x >> 3;            // 0..31
    const int bg  = 4*xcd + (j >> 3);           // 0..31
    const int us  = j & 7;                      // 0..7
    const int b0  = bg * ROWS;
    const int wq  = tid >> 6;                   // k-quarter
    const int l   = tid & 63;
    const int l3  = 128 + (l & 15);

    const float* hin  = temporal + (size_t)(t_ - 1)*HB_;   // deref'd only if t_>0
    float*       hout = temporal + (size_t)t_*HB_;

    // ---- prefetch gate-phase operands (independent of h) ----
    float xg[2][3], bhg[2][3];
    {
        const int u1 = tid % NU, r1 = tid / NU;
        const int ug1 = us*NU + u1;
        const float* xr1 = xproj + ((size_t)(b0 + r1)*T_ + t_)*G3_;
        xg[0][0] = xr1[ug1]; xg[0][1] = xr1[H_+ug1]; xg[0][2] = xr1[2*H_+ug1];
        bhg[0][0] = bh[ug1]; bhg[0][1] = bh[H_+ug1]; bhg[0][2] = bh[2*H_+ug1];
        const int i2 = tid + 256;
        if (i2 < ROWS*NU) {
            const int u2 = i2 % NU, r2 = i2 / NU;
            const int ug2 = us*NU + u2;
            const float* xr2 = xproj + ((size_t)(b0 + r2)*T_ + t_)*G3_;
            xg[1][0] = xr2[ug2]; xg[1][1] = xr2[H_+ug2]; xg[1][2] = xr2[2*H_+ug2];
            bhg[1][0] = bh[ug2]; bhg[1][1] = bh[H_+ug2]; bhg[1][2] = bh[2*H_+ug2];
        }
    }
    // ---- stage h(t-1)[*, b0..b0+7] into LDS (coalesced groups of 8) ----
    if (t_ > 0) {
        #pragma unroll
        for (int ii = 0; ii < 12; ++ii) {
            const int i = tid + ii*256;
            if (i < H_*ROWS) hsl[i] = hin[(size_t)(i >> 3)*B_ + b0 + (i & 7)];
        }
    }
    __syncthreads();

    float acc[ROWS][3];
    #pragma unroll
    for (int r = 0; r < ROWS; ++r) { acc[r][0]=0.f; acc[r][1]=0.f; acc[r][2]=0.f; }

    if (t_ > 0) {
        const float4* hs4 = reinterpret_cast<const float4*>(hsl) + (size_t)wq*184;
        const float4* wp  = Wq + (size_t)(wq*23)*WQCOLS + us*SLSTRIDE;
        // software-pipelined W loads (1 deep)
        float4 w0 = wp[l], w1 = wp[64 + l], w2 = wp[l3];
        for (int kk = 0; kk < 23; ++kk) {
            float4 nw0, nw1, nw2;
            if (kk < 22) {
                const float4* np = wp + (size_t)(kk+1)*WQCOLS;
                nw0 = np[l]; nw1 = np[64 + l]; nw2 = np[l3];
            }
            #pragma unroll
            for (int jk = 0; jk < 4; ++jk) {
                const float4 h0 = hs4[kk*8 + jk*2];
                const float4 h1 = hs4[kk*8 + jk*2 + 1];
                const float wa = F4C(w0, jk), wb = F4C(w1, jk), wc = F4C(w2, jk);
                #pragma unroll
                for (int r = 0; r < 4; ++r) {
                    const float hv = F4C(h0, r);
                    acc[r][0] = fmaf(hv, wa, acc[r][0]);
                    acc[r][1] = fmaf(hv, wb, acc[r][1]);
                    acc[r][2] = fmaf(hv, wc, acc[r][2]);
                }
                #pragma unroll
                for (int r = 0; r < 4; ++r) {
                    const float hv = F4C(h1, r);
                    acc[4+r][0] = fmaf(hv, wa, acc[4+r][0]);
                    acc[4+r][1] = fmaf(hv, wb, acc[4+r][1]);
                    acc[4+r][2] = fmaf(hv, wc, acc[4+r][2]);
                }
            }
            w0 = nw0; w1 = nw1; w2 = nw2;
        }
    }
    // write k-quarter partials (block3: lanes l, l+16, l+32, l+48 same value)
    #pragma unroll
    for (int r = 0; r < ROWS; ++r) {
        part[wq][r][l]      = acc[r][0];
        part[wq][r][64 + l] = acc[r][1];
        part[wq][r][l3]     = acc[r][2];
    }
    __syncthreads();
    // fused gates: 8 rows x 46 units = 368 items
    #pragma unroll
    for (int ii = 0; ii < 2; ++ii) {
        const int i = tid + ii*256;
        if (i < ROWS*NU) {
            const int u = i % NU, r = i / NU;
            const int ug = us*NU + u;
            float s0 = part[0][r][u]      + part[1][r][u]      + part[2][r][u]      + part[3][r][u];
            float s1 = part[0][r][NU+u]   + part[1][r][NU+u]   + part[2][r][NU+u]   + part[3][r][NU+u];
            float s2 = part[0][r][2*NU+u] + part[1][r][2*NU+u] + part[2][r][2*NU+u] + part[3][r][2*NU+u];
            const float rg = 1.f/(1.f + expf(-(xg[ii][0] + s0 + bhg[ii][0])));
            const float zg = 1.f/(1.f + expf(-(xg[ii][1] + s1 + bhg[ii][1])));
            const float ng = tanhf(xg[ii][2] + rg*(s2 + bhg[ii][2]));
            const float hp = (t_ > 0) ? hsl[ug*ROWS + r] : 0.f;
            const float hn = (1.f - zg)*ng + zg*hp;
            hout[(size_t)ug*B_ + b0 + r] = hn;
        }
    }
}

// ---------------------------------------------------------------------------
// K3: heads on temporal [t][u][b] (unchanged, passing)
// ---------------------------------------------------------------------------
__global__ __launch_bounds__(256) void k_heads2(const float* __restrict__ temporal,
                                                const float* __restrict__ Wcat,
                                                const float* __restrict__ bc,
                                                const float* __restrict__ bf,
                                                float* __restrict__ cs,
                                                float* __restrict__ fine_out) {
    const int t = blockIdx.x;       // 0..95
    const int b = threadIdx.x;      // 0..255
    const float* tb = temporal + (size_t)t*HB_ + b;
    float acc[31];
    #pragma unroll
    for (int c = 0; c < 31; ++c) acc[c] = 0.f;
    for (int u = 0; u < H_; ++u) {
        const float x = tb[(size_t)u*B_];
        const float* wrow = Wcat + u*32;
        #pragma unroll
        for (int c = 0; c < 31; ++c) acc[c] = fmaf(x, wrow[c], acc[c]);
    }
    const float l0 = acc[0] + bc[0], l1 = acc[1] + bc[1];
    const float m  = fmaxf(l0, l1);
    const float e0 = expf(l0 - m), e1 = expf(l1 - m);
    const float inv = 1.f/(e0 + e1);
    cs[((size_t)b*T_ + t)*2]     = e0*inv;
    cs[((size_t)b*T_ + t)*2 + 1] = e1*inv;
    #pragma unroll
    for (int c = 2; c < 31; ++c) {
        fine_out[((size_t)b*T_ + t)*NC_ + (c-2)] = 1.f/(1.f + expf(-(acc[c] + bf[c-2])));
    }
}

// ---------------------------------------------------------------------------
// K4: NMS + argmax (unchanged, passing)
// ---------------------------------------------------------------------------
__global__ __launch_bounds__(256) void k_nms(const float* __restrict__ cs,
                                             float* __restrict__ out_dec,
                                             float* __restrict__ out_nms) {
    const int idx = blockIdx.x*256 + threadIdx.x;   // < 24576
    const int t = idx % T_;
    const float bg = cs[idx*2], s1 = cs[idx*2+1];
    float wmin = bg;
    #pragma unroll
    for (int dt = -2; dt <= 2; ++dt) {
        const int tt = t + dt;
        if (dt != 0 && tt >= 0 && tt < T_) wmin = fminf(wmin, cs[(idx + dt)*2]);
    }
    const bool keep = (bg <= wmin);
    out_dec[idx]     = (keep && (s1 > bg)) ? 1.f : 0.f;
    out_nms[idx*2]   = keep ? bg : 0.f;
    out_nms[idx*2+1] = keep ? s1 : 0.f;
}

// ---------------------------------------------------------------------------
extern "C" void kernel_launch(void* const* d_in, const int* in_sizes, int n_in,
                              void* d_out, int out_size, void* d_ws, size_t ws_size,
                              hipStream_t stream) {
    const float* features = (const float*)d_in[0];
    const float* Wi = (const float*)d_in[2];
    const float* Wh = (const float*)d_in[3];
    const float* bi = (const float*)d_in[4];
    const float* bh = (const float*)d_in[5];
    const float* Wc = (const float*)d_in[6];
    const float* bc = (const float*)d_in[7];
    const float* Wf = (const float*)d_in[8];
    const float* bf = (const float*)d_in[9];

    float* out = (float*)d_out;
    float* out_dec  = out;                 // (B,T)     24576
    float* out_nms  = out + BT_;           // (B,T,2)   49152
    float* out_fine = out + BT_ + 2*BT_;   // (B,T,29)  712704

    // workspace layout (floats): xproj | Wq | temporal; xproj reused for
    // Wcat + cs after the GRU (xproj dead by then).
    float* xproj    = (float*)d_ws;
    float4* Wq      = (float4*)(xproj + (size_t)BT_*G3_);
    float* temporal = xproj + (size_t)BT_*G3_ + (size_t)92*WQCOLS*4;
    float* Wcat     = xproj;
    float* cs       = xproj + 12288;

    k_prep_wq<<<414, 256, 0, stream>>>(Wh, Wq);
    k_xproj_gemm<<<dim3(9, 192), 256, 0, stream>>>(features, Wi, bi, xproj);
    for (int t = 0; t < T_; ++t) {
        k_gru_step<<<256, 256, 0, stream>>>(xproj, Wq, bh, temporal, t);
    }
    k_prep_wcat<<<46, 256, 0, stream>>>(Wc, Wf, Wcat);
    k_heads2<<<96, 256, 0, stream>>>(temporal, Wcat, bc, bf, cs, out_fine);
    k_nms<<<96, 256, 0, stream>>>(cs, out_dec, out_nms);
}